// Round 10
// baseline (246.383 us; speedup 1.0000x reference)
//
#include <hip/hip_runtime.h>
#include <hip/hip_bf16.h>

#define NUM_CLASSES 200
#define NF 128
#define NP 2000
#define HW 196
#define MPAD 208        // 13 * 16
#define NB 64
#define EPSV 1e-4f
#define TROW 17         // fp32 staging tile row stride (floats)

typedef __attribute__((ext_vector_type(8))) short short8;   // 8 bf16 = 4 VGPR
typedef __attribute__((ext_vector_type(4))) float f32x4;

static __device__ __forceinline__ unsigned short f2bf(float x) {
    __hip_bfloat16 h = __float2bfloat16(x);
    return __builtin_bit_cast(unsigned short, h);
}

// ---- single fused kernel: one block per image n ------------------------------
// Phase 1: transpose f[n] fp32 -> bf16 XOR-swizzled LDS + exact fp32 xsq.
// Phase 2: 8 p-tiles x (A-frags + exact psq from fp32 protos -> 13x16 MFMA ->
//          min over hw -> min_dist to d_out, sim -> LDS).
// Phase 3: logits[n][:] = sim @ W^T from LDS sim (coalesced W float4 loads).
// No workspace, no intermediate global traffic, one dispatch.
// NOTE: (256,2) — 3 waves/EU spills the A-frags (R7/R8: WRITE_SIZE 65.8 MB).
__global__ __launch_bounds__(256, 2) void kfused(const float* __restrict__ f,
                                                 const float* __restrict__ protos,
                                                 const float* __restrict__ W,
                                                 float* __restrict__ logits,
                                                 float* __restrict__ min_out) {
    __shared__ __align__(16) unsigned short sf[MPAD * NF];  // 53,248 B bf16 B-matrix
    __shared__ float tile[NF * TROW];                       //  8,704 B fp32 staging
    __shared__ float sxsq[MPAD];                            //    832 B
    __shared__ float ssim[2048];                            //  8,192 B sim[p]

    const int n    = blockIdx.x;
    const int t    = threadIdx.x;
    const int wave = t >> 6;
    const int lane = t & 63;
    const int row  = lane & 15;
    const int quad = lane >> 4;

    // ---- phase 1: f[n] -> bf16 [hw][k] swizzled, with inline exact xsq -------
    {
        const int kb   = t >> 2;          // 0..63   (load: k row)
        const int hwl  = (t & 3) * 4;     // 0,4,8,12 (load: hw within chunk)
        const int hwl2 = t >> 4;          // 0..15   (transpose: hw row)
        const int kg   = t & 15;          // 0..15   (transpose: 8-k group)

        #pragma unroll 1
        for (int mt = 0; mt < 13; ++mt) {
            const int hw0 = mt * 16;
            float4 v0 = make_float4(0.f, 0.f, 0.f, 0.f), v1 = v0;
            if (hw0 + hwl + 4 <= HW) {    // HW=196 is a multiple of 4
                v0 = *(const float4*)(f + ((size_t)n * NF + kb) * HW + hw0 + hwl);
                v1 = *(const float4*)(f + ((size_t)n * NF + kb + 64) * HW + hw0 + hwl);
            }
            __syncthreads();   // previous chunk's tile readers are done
            tile[kb * TROW + hwl + 0] = v0.x;
            tile[kb * TROW + hwl + 1] = v0.y;
            tile[kb * TROW + hwl + 2] = v0.z;
            tile[kb * TROW + hwl + 3] = v0.w;
            tile[(kb + 64) * TROW + hwl + 0] = v1.x;
            tile[(kb + 64) * TROW + hwl + 1] = v1.y;
            tile[(kb + 64) * TROW + hwl + 2] = v1.z;
            tile[(kb + 64) * TROW + hwl + 3] = v1.w;
            __syncthreads();
            float xp = 0.f;
            unsigned short u[8];
            #pragma unroll
            for (int j = 0; j < 8; ++j) {
                float val = tile[(kg * 8 + j) * TROW + hwl2];
                xp += val * val;
                u[j] = f2bf(val);
            }
            // XOR-swizzled 16B-unit store: unit kg of row hw lands at kg^hwl2
            ((uint4*)sf)[(hw0 + hwl2) * 16 + (kg ^ hwl2)] = *(uint4*)u;
            xp += __shfl_xor(xp, 1, 64);
            xp += __shfl_xor(xp, 2, 64);
            xp += __shfl_xor(xp, 4, 64);
            xp += __shfl_xor(xp, 8, 64);
            if (kg == 0) sxsq[hw0 + hwl2] = (hw0 + hwl2 < HW) ? xp : 3.0e38f;
        }
    }
    __syncthreads();

    // ---- phase 2: 8 p-tiles of 256 (64 protos per wave per tile) -------------
    const short8* sfv = (const short8*)sf;   // 16 units per 256-B row
    #pragma unroll 1
    for (int pt = 0; pt < 8; ++pt) {
        const int pb = pt * 256 + wave * 64;

        // A frags from fp32 protos (cvt bf16) + exact fp32 psq
        short8 A[4][4];
        float psum[4];
        #pragma unroll
        for (int g = 0; g < 4; ++g) {
            int p = pb + g * 16 + row;
            const float* ap = protos + (size_t)(p < NP ? p : NP - 1) * NF + quad * 8;
            psum[g] = 0.f;
            #pragma unroll
            for (int kk = 0; kk < 4; ++kk) {
                float4 v0 = *(const float4*)(ap + kk * 32);
                float4 v1 = *(const float4*)(ap + kk * 32 + 4);
                psum[g] += v0.x * v0.x + v0.y * v0.y + v0.z * v0.z + v0.w * v0.w
                         + v1.x * v1.x + v1.y * v1.y + v1.z * v1.z + v1.w * v1.w;
                short8 a;
                a[0] = (short)f2bf(v0.x); a[1] = (short)f2bf(v0.y);
                a[2] = (short)f2bf(v0.z); a[3] = (short)f2bf(v0.w);
                a[4] = (short)f2bf(v1.x); a[5] = (short)f2bf(v1.y);
                a[6] = (short)f2bf(v1.z); a[7] = (short)f2bf(v1.w);
                A[g][kk] = a;
            }
            psum[g] += __shfl_xor(psum[g], 16, 64);
            psum[g] += __shfl_xor(psum[g], 32, 64);
        }

        float runmin[4][4];
        #pragma unroll
        for (int g = 0; g < 4; ++g)
            #pragma unroll
            for (int r = 0; r < 4; ++r) runmin[g][r] = 3.0e38f;

        for (int mt = 0; mt < 13; ++mt) {
            const int base = (mt * 16 + row) * 16;
            short8 b0 = sfv[base + ((quad + 0)  ^ row)];
            short8 b1 = sfv[base + ((quad + 4)  ^ row)];
            short8 b2 = sfv[base + ((quad + 8)  ^ row)];
            short8 b3 = sfv[base + ((quad + 12) ^ row)];
            float xv = sxsq[mt * 16 + row];

            #pragma unroll
            for (int g = 0; g < 4; ++g) {
                f32x4 acc = {0.f, 0.f, 0.f, 0.f};
                acc = __builtin_amdgcn_mfma_f32_16x16x32_bf16(A[g][0], b0, acc, 0, 0, 0);
                acc = __builtin_amdgcn_mfma_f32_16x16x32_bf16(A[g][1], b1, acc, 0, 0, 0);
                acc = __builtin_amdgcn_mfma_f32_16x16x32_bf16(A[g][2], b2, acc, 0, 0, 0);
                acc = __builtin_amdgcn_mfma_f32_16x16x32_bf16(A[g][3], b3, acc, 0, 0, 0);
                #pragma unroll
                for (int r = 0; r < 4; ++r)
                    runmin[g][r] = fminf(runmin[g][r], xv - 2.f * acc[r]);
            }
        }

        // min over the 16 D-columns; write min_dist (global) + sim (LDS)
        #pragma unroll
        for (int g = 0; g < 4; ++g) {
            #pragma unroll
            for (int off = 1; off < 16; off <<= 1)
                #pragma unroll
                for (int r = 0; r < 4; ++r)
                    runmin[g][r] = fminf(runmin[g][r], __shfl_xor(runmin[g][r], off, 64));
            #pragma unroll
            for (int r = 0; r < 4; ++r) {
                float psq_sel = __shfl(psum[g], 20 * quad + r, 64);
                int p = pb + g * 16 + quad * 4 + r;
                if (row == 0 && p < NP) {
                    float m = fmaxf(runmin[g][r] + psq_sel, 0.f);
                    min_out[(size_t)n * NP + p] = m;
                    ssim[p] = logf((m + 1.f) / (m + EPSV));
                }
            }
        }
    }
    __syncthreads();

    // ---- phase 3: logits[n][c] = sum_p ssim[p] * W[c][p], 50 classes/wave ----
    {
        const float4* s4 = (const float4*)ssim;
        #pragma unroll 1
        for (int ci = 0; ci < 50; ++ci) {
            const int c = wave * 50 + ci;
            const float4* w4 = (const float4*)(W + (size_t)c * NP);
            float acc = 0.f;
            #pragma unroll
            for (int j = 0; j < 8; ++j) {
                int idx = j * 64 + lane;
                if (idx < NP / 4) {
                    float4 wv = w4[idx];
                    float4 sv = s4[idx];
                    acc += wv.x * sv.x + wv.y * sv.y + wv.z * sv.z + wv.w * sv.w;
                }
            }
            #pragma unroll
            for (int off = 32; off; off >>= 1) acc += __shfl_down(acc, off, 64);
            if (lane == 0) logits[(size_t)n * NUM_CLASSES + c] = acc;
        }
    }
}

extern "C" void kernel_launch(void* const* d_in, const int* in_sizes, int n_in,
                              void* d_out, int out_size, void* d_ws, size_t ws_size,
                              hipStream_t stream) {
    const float* f      = (const float*)d_in[0];  // 64x128x14x14
    const float* protos = (const float*)d_in[1];  // 2000x128
    const float* W      = (const float*)d_in[2];  // 200x2000

    float* logits   = (float*)d_out;                          // 64*200
    float* min_dist = (float*)d_out + NB * NUM_CLASSES;       // 64*2000

    (void)d_ws; (void)ws_size;  // no workspace needed — everything block-local

    kfused<<<NB, 256, 0, stream>>>(f, protos, W, logits, min_dist);
}